// Round 10
// baseline (389.245 us; speedup 1.0000x reference)
//
#include <hip/hip_runtime.h>
#include <cstdint>
#include <cstddef>

// CausalAttention B=4 S=2048 D=1024.
// d_out = [context (4*2048*1024 f32)] ++ [attn_scores (4*2048*2048 f32)]
//
// scores = x M x^T, M[d,e] = sum_i Wq[d,i] Wk[e,i]:
//   M^T = bt(A=Wk, B=Wq)   (split bf16 3-pass; mu fused via atomics)
//   N~  = x M - sq*mu^T    (split; mean-deflated)
//   S   = N~ x^T + sq*u    (split, lower-tri; exact f32 rank-1 add-back)
// Round-10: k_gemm_n was the last 2-blocks/CU GEMM on the BK=32 profile
// (32 vmcnt(0)+barrier drains/block). Same k-plane BK=64 treatment that
// won on ctx in r9: [2][128][32] planes x 4 arrays (hi/lo x A/B), 16
// copies + 96 MFMA per barrier, barriers 32->16, occupancy unchanged
// (grid-capped at 2/CU anyway).

#define S_LEN 2048
#define D_DIM 1024
#define NBATCH 4
#define MEG (1024 * 1024)

typedef __attribute__((ext_vector_type(4))) float floatx4;
typedef __attribute__((ext_vector_type(8))) __bf16 bf16x8;
typedef __attribute__((ext_vector_type(8))) short short8v;

__device__ __forceinline__ unsigned short f2bf(float f) {
  union { float f; unsigned u; } v; v.f = f;
  unsigned r = v.u + 0x7FFF + ((v.u >> 16) & 1);   // round-to-nearest-even
  return (unsigned short)(r >> 16);
}
__device__ __forceinline__ float bf2f(unsigned short h) {
  union { unsigned u; float f; } v; v.u = ((unsigned)h) << 16; return v.f;
}

__device__ __forceinline__ void async_copy16(const void* g, void* l) {
  __builtin_amdgcn_global_load_lds(
      (const __attribute__((address_space(1))) void*)g,
      (__attribute__((address_space(3))) void*)l, 16, 0, 0);
}

// ================= 256-thread, 128x128-tile cores (BK=32) =================

__device__ __forceinline__ void gemm_bt_core(
    const short* __restrict__ A, const short* __restrict__ B,
    int lda, int ldb, int kIters, int blockM, int blockN,
    short (*As)[32], short (*Bs)[32], floatx4 (&acc)[4][4])
{
  const int tid  = threadIdx.x;
  const int lane = tid & 63;
  const int wave = tid >> 6;
  const int wm = (wave >> 1) * 64;
  const int wn = (wave & 1) * 64;
  const int fm = lane & 15;
  const int fk = (lane >> 4) * 8;
  const int r0 = tid >> 2;
  const int c0 = (tid & 3) * 8;

  floatx4 zero = {0.f, 0.f, 0.f, 0.f};
  #pragma unroll
  for (int i = 0; i < 4; ++i)
    #pragma unroll
    for (int j = 0; j < 4; ++j)
      acc[i][j] = zero;

  const short* a0 = A + (size_t)(blockM + r0) * lda + c0;
  const short* a1 = a0 + (size_t)64 * lda;
  const short* b0 = B + (size_t)(blockN + r0) * ldb + c0;
  const short* b1 = b0 + (size_t)64 * ldb;
  short* as0 = &As[r0][c0];
  short* as1 = &As[r0 + 64][c0];
  short* bs0 = &Bs[r0][c0];
  short* bs1 = &Bs[r0 + 64][c0];

  for (int kt = 0; kt < kIters; ++kt) {
    const int kb = kt * 32;
    async_copy16(a0 + kb, as0);
    async_copy16(a1 + kb, as1);
    async_copy16(b0 + kb, bs0);
    async_copy16(b1 + kb, bs1);
    __syncthreads();
    bf16x8 af[4], bfr[4];
    #pragma unroll
    for (int i = 0; i < 4; ++i)
      af[i] = *(const bf16x8*)(&As[wm + i * 16 + fm][fk]);
    #pragma unroll
    for (int j = 0; j < 4; ++j)
      bfr[j] = *(const bf16x8*)(&Bs[wn + j * 16 + fm][fk]);
    #pragma unroll
    for (int i = 0; i < 4; ++i)
      #pragma unroll
      for (int j = 0; j < 4; ++j)
        acc[i][j] = __builtin_amdgcn_mfma_f32_16x16x32_bf16(af[i], bfr[j], acc[i][j], 0, 0, 0);
    __syncthreads();
  }
}

__device__ __forceinline__ void gemm_bt_split_core(
    const short* __restrict__ Ah, const short* __restrict__ Al,
    const short* __restrict__ Bh, const short* __restrict__ Bl,
    int lda, int ldb, int kIters, int blockM, int blockN,
    short (*AsH)[32], short (*AsL)[32], short (*BsH)[32], short (*BsL)[32],
    floatx4 (&acc)[4][4])
{
  const int tid  = threadIdx.x;
  const int lane = tid & 63;
  const int wave = tid >> 6;
  const int wm = (wave >> 1) * 64;
  const int wn = (wave & 1) * 64;
  const int fm = lane & 15;
  const int fk = (lane >> 4) * 8;
  const int r0 = tid >> 2;
  const int c0 = (tid & 3) * 8;

  floatx4 zero = {0.f, 0.f, 0.f, 0.f};
  #pragma unroll
  for (int i = 0; i < 4; ++i)
    #pragma unroll
    for (int j = 0; j < 4; ++j)
      acc[i][j] = zero;

  const size_t oa0 = (size_t)(blockM + r0) * lda + c0;
  const size_t oa1 = oa0 + (size_t)64 * lda;
  const size_t ob0 = (size_t)(blockN + r0) * ldb + c0;
  const size_t ob1 = ob0 + (size_t)64 * ldb;
  short* lah0 = &AsH[r0][c0]; short* lah1 = &AsH[r0 + 64][c0];
  short* lal0 = &AsL[r0][c0]; short* lal1 = &AsL[r0 + 64][c0];
  short* lbh0 = &BsH[r0][c0]; short* lbh1 = &BsH[r0 + 64][c0];
  short* lbl0 = &BsL[r0][c0]; short* lbl1 = &BsL[r0 + 64][c0];

  for (int kt = 0; kt < kIters; ++kt) {
    const int kb = kt * 32;
    async_copy16(Ah + oa0 + kb, lah0);
    async_copy16(Ah + oa1 + kb, lah1);
    async_copy16(Al + oa0 + kb, lal0);
    async_copy16(Al + oa1 + kb, lal1);
    async_copy16(Bh + ob0 + kb, lbh0);
    async_copy16(Bh + ob1 + kb, lbh1);
    async_copy16(Bl + ob0 + kb, lbl0);
    async_copy16(Bl + ob1 + kb, lbl1);
    __syncthreads();
    bf16x8 ah[4], al[4], bh[4], bl[4];
    #pragma unroll
    for (int i = 0; i < 4; ++i) {
      ah[i] = *(const bf16x8*)(&AsH[wm + i * 16 + fm][fk]);
      al[i] = *(const bf16x8*)(&AsL[wm + i * 16 + fm][fk]);
    }
    #pragma unroll
    for (int j = 0; j < 4; ++j) {
      bh[j] = *(const bf16x8*)(&BsH[wn + j * 16 + fm][fk]);
      bl[j] = *(const bf16x8*)(&BsL[wn + j * 16 + fm][fk]);
    }
    #pragma unroll
    for (int i = 0; i < 4; ++i)
      #pragma unroll
      for (int j = 0; j < 4; ++j) {
        acc[i][j] = __builtin_amdgcn_mfma_f32_16x16x32_bf16(ah[i], bh[j], acc[i][j], 0, 0, 0);
        acc[i][j] = __builtin_amdgcn_mfma_f32_16x16x32_bf16(ah[i], bl[j], acc[i][j], 0, 0, 0);
        acc[i][j] = __builtin_amdgcn_mfma_f32_16x16x32_bf16(al[i], bh[j], acc[i][j], 0, 0, 0);
      }
    __syncthreads();
  }
}

// ---------------- W conversions ----------------
// [0,512): Wq split. [512,1024): Wk split. [1024,2048): Wv transpose (hi only);
// block 1024 also zeroes muSum.

__global__ __launch_bounds__(256) void k_cvt_w(
    const float* __restrict__ wq, const float* __restrict__ wk,
    const float* __restrict__ wv,
    short* __restrict__ wqh, short* __restrict__ wql,
    short* __restrict__ wkh, short* __restrict__ wkl,
    short* __restrict__ wvt, float* __restrict__ muSum)
{
  const int bid = blockIdx.x;
  const int tid = threadIdx.x;
  if (bid < 1024) {
    const float4* src;
    short *dh, *dl;
    size_t idx;
    if (bid < 512) {
      idx = (size_t)bid * 256 + tid;
      src = (const float4*)wq; dh = wqh; dl = wql;
    } else {
      idx = (size_t)(bid - 512) * 256 + tid;
      src = (const float4*)wk; dh = wkh; dl = wkl;
    }
    const float4 u4 = src[idx * 2];
    const float4 w4 = src[idx * 2 + 1];
    float f[8] = {u4.x, u4.y, u4.z, u4.w, w4.x, w4.y, w4.z, w4.w};
    short8v oh, ol;
    #pragma unroll
    for (int e = 0; e < 8; ++e) {
      const unsigned short h = f2bf(f[e]);
      oh[e] = (short)h;
      ol[e] = (short)f2bf(f[e] - bf2f(h));
    }
    *(short8v*)(dh + idx * 8) = oh;
    *(short8v*)(dl + idx * 8) = ol;
  } else {
    if (bid == 1024) {   // zero muSum before k_m_cvtx's atomics
      float4 z = {0.f, 0.f, 0.f, 0.f};
      ((float4*)muSum)[tid] = z;
    }
    const int rem = bid - 1024;
    const int bx = rem & 31, by = rem >> 5;
    const int tx = tid & 31, ty = tid >> 5;  // 32 x 8
    __shared__ float tile[32][33];
    const int colIn = bx * 32 + tx;
    #pragma unroll
    for (int i = 0; i < 4; ++i) {
      const int rowIn = by * 32 + ty + i * 8;
      tile[ty + i * 8][tx] = wv[(size_t)rowIn * D_DIM + colIn];
    }
    __syncthreads();
    const int colOut = by * 32 + tx;   // d (input row of Wv)
    #pragma unroll
    for (int i = 0; i < 4; ++i) {
      const int rowOut = bx * 32 + ty + i * 8;  // n (output col of Wv)
      wvt[(size_t)rowOut * D_DIM + colOut] = (short)f2bf(tile[tx][ty + i * 8]);
    }
  }
}

// ---------------- M^T GEMM (64 tiles) + x hi/lo split (4096 blocks), fused ----------------

__global__ __launch_bounds__(256) void k_m_cvtx(
    const short* __restrict__ wqh, const short* __restrict__ wql,
    const short* __restrict__ wkh, const short* __restrict__ wkl,
    short* __restrict__ mth, short* __restrict__ mtl,
    float* __restrict__ muSum,
    const float4* __restrict__ x,
    short* __restrict__ xh, short* __restrict__ xl)
{
  __shared__ alignas(16) short AsH[128][32];
  __shared__ alignas(16) short AsL[128][32];
  __shared__ alignas(16) short BsH[128][32];
  __shared__ alignas(16) short BsL[128][32];
  const int g = blockIdx.x;
  const int tid = threadIdx.x;

  if (g < 64) {
    floatx4 acc[4][4];
    const int blockM = (g >> 3) * 128;   // e
    const int blockN = (g & 7) * 128;    // d
    gemm_bt_split_core(wkh, wkl, wqh, wql,
                       D_DIM, D_DIM, D_DIM / 32, blockM, blockN,
                       AsH, AsL, BsH, BsL, acc);

    const int lane = tid & 63, wave = tid >> 6;
    const int wm = (wave >> 1) * 64, wn = (wave & 1) * 64;
    const int rb = wm + ((lane >> 4) << 2);
    const int cb = wn + (lane & 15);
    #pragma unroll
    for (int i = 0; i < 4; ++i)
      #pragma unroll
      for (int j = 0; j < 4; ++j) {
        const int n = blockN + cb + j * 16;
        #pragma unroll
        for (int r = 0; r < 4; ++r) {
          const int m = blockM + rb + i * 16 + r;
          const float f = acc[i][j][r];
          const unsigned short h = f2bf(f);
          mth[(size_t)m * D_DIM + n] = (short)h;
          mtl[(size_t)m * D_DIM + n] = (short)f2bf(f - bf2f(h));
        }
      }
    // mu partials: per row e, sum over this block's 128 d-cols
    #pragma unroll
    for (int i = 0; i < 4; ++i)
      #pragma unroll
      for (int r = 0; r < 4; ++r) {
        float v = acc[i][0][r] + acc[i][1][r] + acc[i][2][r] + acc[i][3][r];
        v += __shfl_xor(v, 1); v += __shfl_xor(v, 2);
        v += __shfl_xor(v, 4); v += __shfl_xor(v, 8);
        if ((lane & 15) == 0)
          atomicAdd(&muSum[blockM + rb + i * 16 + r], v);
      }
  } else {
    const size_t idx = (size_t)(g - 64) * 256 + tid;
    const float4 u4 = x[idx * 2];
    const float4 w4 = x[idx * 2 + 1];
    float f[8] = {u4.x, u4.y, u4.z, u4.w, w4.x, w4.y, w4.z, w4.w};
    short8v oh, ol;
    #pragma unroll
    for (int e = 0; e < 8; ++e) {
      const unsigned short h = f2bf(f[e]);
      oh[e] = (short)h;
      ol[e] = (short)f2bf(f[e] - bf2f(h));
    }
    *(short8v*)(xh + idx * 8) = oh;
    *(short8v*)(xl + idx * 8) = ol;
  }
}

// ---------------- per-row stats over reconstructed split-x ----------------

__global__ __launch_bounds__(256) void k_rowstats(
    const short* __restrict__ xh, const short* __restrict__ xl,
    const float* __restrict__ muSum, float* __restrict__ sq, float* __restrict__ u)
{
  const int r = blockIdx.x, tid = threadIdx.x;
  const ushort4 h = *(const ushort4*)(xh + (size_t)r * D_DIM + tid * 4);
  const ushort4 l = *(const ushort4*)(xl + (size_t)r * D_DIM + tid * 4);
  const float4 m4 = *(const float4*)(muSum + tid * 4);
  const float x0 = bf2f(h.x) + bf2f(l.x);
  const float x1 = bf2f(h.y) + bf2f(l.y);
  const float x2 = bf2f(h.z) + bf2f(l.z);
  const float x3 = bf2f(h.w) + bf2f(l.w);
  float s = x0 + x1 + x2 + x3;
  float uu = m4.x * x0 + m4.y * x1 + m4.z * x2 + m4.w * x3;
  #pragma unroll
  for (int off = 32; off > 0; off >>= 1) {
    s  += __shfl_xor(s, off);
    uu += __shfl_xor(uu, off);
  }
  __shared__ float ps[4], pu[4];
  if ((tid & 63) == 0) { ps[tid >> 6] = s; pu[tid >> 6] = uu; }
  __syncthreads();
  if (tid == 0) {
    sq[r] = ps[0] + ps[1] + ps[2] + ps[3];
    u[r]  = (pu[0] + pu[1] + pu[2] + pu[3]) * (1.0f / 1024.0f);
  }
}

// ---------------- N~ = x M - sq mu^T, split, BK=64 k-plane LDS ----------------
// LDS planes [2][128][32] per array; global_load_lds dst stays wave-linear,
// per-chunk SOURCE addresses remapped (same pattern as ctx's r9 core).

__global__ __launch_bounds__(256) void k_gemm_n(
    const short* __restrict__ xh, const short* __restrict__ xl,
    const short* __restrict__ mth, const short* __restrict__ mtl,
    const float* __restrict__ sq, const float* __restrict__ muSum,
    short* __restrict__ nh, short* __restrict__ nl)
{
  __shared__ alignas(16) short AsH[2][128][32];
  __shared__ alignas(16) short AsL[2][128][32];
  __shared__ alignas(16) short BsH[2][128][32];
  __shared__ alignas(16) short BsL[2][128][32];
  floatx4 acc[4][4];
  const int blockM = blockIdx.y * 128;   // global row (b,s)
  const int blockN = blockIdx.x * 128;   // e

  const int tid = threadIdx.x, lane = tid & 63, wave = tid >> 6;
  const int wm = (wave >> 1) * 64, wn = (wave & 1) * 64;
  const int fm = lane & 15, fk = (lane >> 4) * 8;
  const int r0 = tid >> 2, c0 = (tid & 3) * 8;

  floatx4 zero = {0.f, 0.f, 0.f, 0.f};
  #pragma unroll
  for (int i = 0; i < 4; ++i)
    #pragma unroll
    for (int j = 0; j < 4; ++j)
      acc[i][j] = zero;

  const short* ah0 = xh  + (size_t)(blockM + r0) * D_DIM + c0;
  const short* al0 = xl  + (size_t)(blockM + r0) * D_DIM + c0;
  const short* bh0 = mth + (size_t)(blockN + r0) * D_DIM + c0;
  const short* bl0 = mtl + (size_t)(blockN + r0) * D_DIM + c0;
  const size_t rstep = (size_t)64 * D_DIM;

  short* ahB = &AsH[0][0][0];
  short* alB = &AsL[0][0][0];
  short* bhB = &BsH[0][0][0];
  short* blB = &BsL[0][0][0];
  const int l0 = tid * 8, l1 = (tid + 256) * 8, l2 = (tid + 512) * 8, l3 = (tid + 768) * 8;

  for (int kt = 0; kt < 16; ++kt) {     // BK=64
    const int kb = kt * 64;
    async_copy16(ah0 + kb, ahB + l0);
    async_copy16(ah0 + rstep + kb, ahB + l1);
    async_copy16(ah0 + kb + 32, ahB + l2);
    async_copy16(ah0 + rstep + kb + 32, ahB + l3);
    async_copy16(al0 + kb, alB + l0);
    async_copy16(al0 + rstep + kb, alB + l1);
    async_copy16(al0 + kb + 32, alB + l2);
    async_copy16(al0 + rstep + kb + 32, alB + l3);
    async_copy16(bh0 + kb, bhB + l0);
    async_copy16(bh0 + rstep + kb, bhB + l1);
    async_copy16(bh0 + kb + 32, bhB + l2);
    async_copy16(bh0 + rstep + kb + 32, bhB + l3);
    async_copy16(bl0 + kb, blB + l0);
    async_copy16(bl0 + rstep + kb, blB + l1);
    async_copy16(bl0 + kb + 32, blB + l2);
    async_copy16(bl0 + rstep + kb + 32, blB + l3);
    __syncthreads();
    #pragma unroll
    for (int ks = 0; ks < 2; ++ks) {
      bf16x8 ah[4], al[4], bh[4], bl[4];
      #pragma unroll
      for (int i = 0; i < 4; ++i) {
        ah[i] = *(const bf16x8*)(&AsH[ks][wm + i * 16 + fm][fk]);
        al[i] = *(const bf16x8*)(&AsL[ks][wm + i * 16 + fm][fk]);
      }
      #pragma unroll
      for (int j = 0; j < 4; ++j) {
        bh[j] = *(const bf16x8*)(&BsH[ks][wn + j * 16 + fm][fk]);
        bl[j] = *(const bf16x8*)(&BsL[ks][wn + j * 16 + fm][fk]);
      }
      #pragma unroll
      for (int i = 0; i < 4; ++i)
        #pragma unroll
        for (int j = 0; j < 4; ++j) {
          acc[i][j] = __builtin_amdgcn_mfma_f32_16x16x32_bf16(ah[i], bh[j], acc[i][j], 0, 0, 0);
          acc[i][j] = __builtin_amdgcn_mfma_f32_16x16x32_bf16(ah[i], bl[j], acc[i][j], 0, 0, 0);
          acc[i][j] = __builtin_amdgcn_mfma_f32_16x16x32_bf16(al[i], bh[j], acc[i][j], 0, 0, 0);
        }
    }
    __syncthreads();
  }

  const int rb = wm + ((lane >> 4) << 2);
  const int cb = wn + (lane & 15);
  #pragma unroll
  for (int i = 0; i < 4; ++i)
    #pragma unroll
    for (int j = 0; j < 4; ++j) {
      const int n = blockN + cb + j * 16;
      const float muv = muSum[n] * (1.0f / 1024.0f);
      #pragma unroll
      for (int r = 0; r < 4; ++r) {
        const int m = blockM + rb + i * 16 + r;
        const float f = acc[i][j][r] - sq[m] * muv;   // deflate
        const unsigned short h = f2bf(f);
        nh[(size_t)m * D_DIM + n] = (short)h;
        nl[(size_t)m * D_DIM + n] = (short)f2bf(f - bf2f(h));
      }
    }
}

// ---------------- fused scores (544, band-ordered) + V (512, tail filler) ----------------

__global__ __launch_bounds__(256) void k_gemm_sv(
    const short* __restrict__ nh, const short* __restrict__ nl,
    const short* __restrict__ xh, const short* __restrict__ xl,
    const float* __restrict__ sq, const float* __restrict__ u,
    const short* __restrict__ wvt, float* __restrict__ attn,
    short* __restrict__ vt)
{
  __shared__ alignas(16) short AsH[128][32];
  __shared__ alignas(16) short AsL[128][32];
  __shared__ alignas(16) short BsH[128][32];
  __shared__ alignas(16) short BsL[128][32];
  floatx4 acc[4][4];

  const int g = blockIdx.x;
  const int tid = threadIdx.x, lane = tid & 63, wave = tid >> 6;
  const int wm = (wave >> 1) * 64, wn = (wave & 1) * 64;
  const int rb = wm + ((lane >> 4) << 2);
  const int cb = wn + (lane & 15);

  if (g < 544) {
    const int item = (g & 7) * 68 + (g >> 3);   // per-XCD chunk (batch = 2 XCDs)
    const int b = item / 136;
    int t = item - b * 136;
    int band = 0;
    while (t >= 58 - 16 * band) { t -= 58 - 16 * band; ++band; }
    int bi = band * 4;
    for (;;) {
      const int w = bi - band * 4 + 1;
      const int ww = w < 4 ? w : 4;
      if (t < ww) break;
      t -= ww; ++bi;
    }
    const int bj = band * 4 + t;

    const size_t boff = (size_t)b * S_LEN * D_DIM;
    gemm_bt_split_core(nh + boff, nl + boff, xh + boff, xl + boff,
                       D_DIM, D_DIM, D_DIM / 32, bi * 128, bj * 128,
                       AsH, AsL, BsH, BsL, acc);

    float* out = attn + (size_t)b * S_LEN * S_LEN;
    const int rowBase = (b << 11) + bi * 128;
    const int colBase = (b << 11) + bj * 128;
    #pragma unroll
    for (int j = 0; j < 4; ++j) {
      const int n = bj * 128 + cb + j * 16;
      const float uv = u[colBase + cb + j * 16];
      #pragma unroll
      for (int i = 0; i < 4; ++i)
        #pragma unroll
        for (int r = 0; r < 4; ++r) {
          const int m = bi * 128 + rb + i * 16 + r;
          const float sv = sq[rowBase + rb + i * 16 + r];
          out[(size_t)m * S_LEN + n] = acc[i][j][r] + sv * uv;  // raw scores
        }
    }
  } else {
    const int vb = g - 544;
    const int blockM = (vb >> 3) * 128;   // global row over 8192
    const int blockN = (vb & 7) * 128;    // d
    gemm_bt_core(xh, wvt, D_DIM, D_DIM, D_DIM / 32, blockM, blockN,
                 AsH, BsH, acc);
    #pragma unroll
    for (int i = 0; i < 4; ++i)
      #pragma unroll
      for (int j = 0; j < 4; ++j) {
        const int n = blockN + cb + j * 16;   // d index
        const int m0 = blockM + rb + i * 16;  // global row, 4-aligned
        const int b = m0 >> 11;
        const int s0 = m0 & (S_LEN - 1);
        ushort4 pk;
        pk.x = f2bf(acc[i][j][0]); pk.y = f2bf(acc[i][j][1]);
        pk.z = f2bf(acc[i][j][2]); pk.w = f2bf(acc[i][j][3]);
        *(ushort4*)(vt + ((size_t)b * D_DIM + n) * S_LEN + s0) = pk;
      }
  }
}

// ---------------- softmax: prefix-only reads, band-limited pb writes ----------------

__global__ __launch_bounds__(256) void k_softmax(float* __restrict__ attn,
                                                 short* __restrict__ pb) {
  const int b = blockIdx.x >> 11;
  const int q = blockIdx.x & (S_LEN - 1);
  float* row  = attn + ((size_t)b * S_LEN + q) * S_LEN;
  short* prow = pb   + ((size_t)b * S_LEN + q) * S_LEN;
  const int tid = threadIdx.x;
  const int k0 = tid * 8;
  const int kBand = ((q >> 7) + 1) << 7;   // 128-aligned band end
  __shared__ float sMax[4], sSum[4];

  float v[8];
  if (k0 <= q) {               // load only the live prefix
    const float4 a0 = *(const float4*)(row + k0);
    const float4 a1 = *(const float4*)(row + k0 + 4);
    v[0] = a0.x; v[1] = a0.y; v[2] = a0.z; v[3] = a0.w;
    v[4] = a1.x; v[5] = a1.y; v[6] = a1.z; v[7] = a1.w;
  } else {
    #pragma unroll
    for (int e = 0; e < 8; ++e) v[e] = -3.0e38f;
  }

  float mx = -3.0e38f;
  #pragma unroll
  for (int e = 0; e < 8; ++e) {
    v[e] = (k0 + e <= q) ? v[e] : -3.0e38f;
    mx = fmaxf(mx, v[e]);
  }
  #pragma unroll
  for (int off = 32; off > 0; off >>= 1) mx = fmaxf(mx, __shfl_xor(mx, off));
  if ((tid & 63) == 0) sMax[tid >> 6] = mx;
  __syncthreads();
  mx = fmaxf(fmaxf(sMax[0], sMax[1]), fmaxf(sMax[2], sMax[3]));

  float s = 0.f;
  #pragma unroll
  for (int e = 0; e < 8; ++e) {
    const float p = (k0 + e <= q) ? __expf((v[e] - mx) * 0.03125f) : 0.f;
    v[e] = p;
    s += p;
  }
  #pragma unroll
  for (int off = 32; off > 0; off >>= 1) s += __shfl_xor(s, off);
  if ((tid & 63) == 0) sSum[tid >> 6] = s;
  __syncthreads();
  s = sSum[0] + sSum[1] + sSum[2] + sSum[3];
  const float inv = 1.0f / s;

  float o[8];
  #pragma unroll
  for (int e = 0; e < 8; ++e) o[e] = v[e] * inv;   // 0 for masked
  float4 w0 = {o[0], o[1], o[2], o[3]};
  float4 w1 = {o[4], o[5], o[6], o[7]};
  *(float4*)(row + k0) = w0;
  *(float4*)(row + k0 + 4) = w1;
  if (k0 < kBand) {
    ushort4 p0, p1;
    p0.x = f2bf(o[0]); p0.y = f2bf(o[1]); p0.z = f2bf(o[2]); p0.w = f2bf(o[3]);
    p1.x = f2bf(o[4]); p1.y = f2bf(o[5]); p1.z = f2bf(o[6]); p1.w = f2bf(o[7]);
    *(ushort4*)(prow + k0) = p0;
    *(ushort4*)(prow + k0 + 4) = p1;
  }
}

// ---------------- context = P @ V, 128^2, BK=64 k-plane LDS, heavy first ----------------

__global__ __launch_bounds__(256) void k_gemm_ctx(
    const short* __restrict__ pb, const short* __restrict__ vt,
    float* __restrict__ ctx)
{
  __shared__ alignas(16) short As2[2][128][32];
  __shared__ alignas(16) short Bs2[2][128][32];
  floatx4 acc[4][4];
  const int b = blockIdx.z;
  const int by = 15 - blockIdx.y;        // heavy K-loops dispatched first
  const int blockM = by * 128;           // q
  const int blockN = blockIdx.x * 128;   // d
  const int kIters = (by + 1) * 2;       // BK=64; k <= blockM+127 only
  const short* A = pb + (size_t)b * S_LEN * S_LEN;
  const short* B = vt + (size_t)b * D_DIM * S_LEN;

  const int tid = threadIdx.x, lane = tid & 63, wave = tid >> 6;
  const int wm = (wave >> 1) * 64, wn = (wave & 1) * 64;
  const int fm = lane & 15, fk = (lane >> 4) * 8;
  const int r0 = tid >> 2, c0 = (tid & 3) * 8;

  floatx4 zero = {0.f, 0.f, 0.f, 0.f};
  #pragma unroll
  for (int i = 0; i < 4; ++i)
    #pragma unroll
    for (int j = 0; j < 4; ++j)
      acc[i][j] = zero;

  const short* a0 = A + (size_t)(blockM + r0) * S_LEN + c0;
  const short* a1 = a0 + (size_t)64 * S_LEN;
  const short* b0 = B + (size_t)(blockN + r0) * S_LEN + c0;
  const short* b1 = b0 + (size_t)64 * S_LEN;
  short* asBase = &As2[0][0][0];
  short* bsBase = &Bs2[0][0][0];
  short* as0 = asBase + (size_t)tid * 8;
  short* as1 = asBase + (size_t)(tid + 256) * 8;
  short* as2 = asBase + (size_t)(tid + 512) * 8;
  short* as3 = asBase + (size_t)(tid + 768) * 8;
  short* bs0 = bsBase + (size_t)tid * 8;
  short* bs1 = bsBase + (size_t)(tid + 256) * 8;
  short* bs2 = bsBase + (size_t)(tid + 512) * 8;
  short* bs3 = bsBase + (size_t)(tid + 768) * 8;

  for (int kt = 0; kt < kIters; ++kt) {
    const int kb = kt * 64;
    async_copy16(a0 + kb, as0);
    async_copy16(a1 + kb, as1);
    async_copy16(a0 + kb + 32, as2);
    async_copy16(a1 + kb + 32, as3);
    async_copy16(b0 + kb, bs0);
    async_copy16(b1 + kb, bs1);
    async_copy16(b0 + kb + 32, bs2);
    async_copy16(b1 + kb + 32, bs3);
    __syncthreads();
    #pragma unroll
    for (int ks = 0; ks < 2; ++ks) {
      bf16x8 af[4], bfr[4];
      #pragma unroll
      for (int i = 0; i < 4; ++i)
        af[i] = *(const bf16x8*)(&As2[ks][wm + i * 16 + fm][fk]);
      #pragma unroll
      for (int j = 0; j < 4; ++j)
        bfr[j] = *(const bf16x8*)(&Bs2[ks][wn + j * 16 + fm][fk]);
      #pragma unroll
      for (int i = 0; i < 4; ++i)
        #pragma unroll
        for (int j = 0; j < 4; ++j)
          acc[i][j] = __builtin_amdgcn_mfma_f32_16x16x32_bf16(af[i], bfr[j], acc[i][j], 0, 0, 0);
    }
    __syncthreads();
  }

  float* out = ctx + (size_t)b * S_LEN * D_DIM;
  const int rb = wm + ((lane >> 4) << 2);
  const int cb = wn + (lane & 15);
  #pragma unroll
  for (int i = 0; i < 4; ++i)
    #pragma unroll
    for (int j = 0; j < 4; ++j) {
      const int n = blockN + cb + j * 16;
      #pragma unroll
      for (int r = 0; r < 4; ++r) {
        const int m = blockM + rb + i * 16 + r;
        out[(size_t)m * D_DIM + n] = acc[i][j][r];
      }
    }
}

// ---------------- launch ----------------

extern "C" void kernel_launch(void* const* d_in, const int* in_sizes, int n_in,
                              void* d_out, int out_size, void* d_ws, size_t ws_size,
                              hipStream_t stream) {
  const float* x  = (const float*)d_in[0];
  const float* wq = (const float*)d_in[1];
  const float* wk = (const float*)d_in[2];
  const float* wv = (const float*)d_in[3];

  float* out  = (float*)d_out;
  float* ctx  = out;                                       // [4,2048,1024]
  float* attn = out + (size_t)NBATCH * S_LEN * D_DIM;      // [4,2048,2048]

  // workspace (shorts), ~94 MiB; pb aliases nh/nl (dead after scores GEMM)
  short* ws  = (short*)d_ws;
  short* xh  = ws;                                  // 8M
  short* xl  = xh + (size_t)8 * MEG;                // 8M
  short* wqh = xl + (size_t)8 * MEG;                // 1M Wq hi (original layout)
  short* wql = wqh + (size_t)1 * MEG;               // 1M Wq lo
  short* wkh = wql + (size_t)1 * MEG;               // 1M Wk hi
  short* wkl = wkh + (size_t)1 * MEG;               // 1M Wk lo
  short* wvt = wkl + (size_t)1 * MEG;               // 1M Wv^T hi
  short* mth = wvt + (size_t)1 * MEG;               // 1M M^T hi
  short* mtl = mth + (size_t)1 * MEG;               // 1M M^T lo
  short* nh  = mtl + (size_t)1 * MEG;               // 8M N~ hi
  short* nl  = nh + (size_t)8 * MEG;                // 8M N~ lo
  short* vt  = nl + (size_t)8 * MEG;                // 8M V^T [b,d,s]
  short* pb  = nh;                                  // 16M alias (nh+nl)
  float* fb  = (float*)(vt + (size_t)8 * MEG);
  float* muS = fb;                                  // 1024 (sum over d, not mean)
  float* sq  = fb + 1024;                           // 8192
  float* u   = sq + 8192;                           // 8192

  k_cvt_w<<<2048, 256, 0, stream>>>(wq, wk, wv, wqh, wql, wkh, wkl, wvt, muS);
  k_m_cvtx<<<4160, 256, 0, stream>>>(wqh, wql, wkh, wkl, mth, mtl, muS,
                                     (const float4*)x, xh, xl);
  k_rowstats<<<8192, 256, 0, stream>>>(xh, xl, muS, sq, u);
  k_gemm_n<<<dim3(8, 64), 256, 0, stream>>>(xh, xl, mth, mtl, sq, muS, nh, nl);
  k_gemm_sv<<<1056, 256, 0, stream>>>(nh, nl, xh, xl, sq, u, wvt, attn, vt);
  k_softmax<<<NBATCH * S_LEN, 256, 0, stream>>>(attn, pb);
  k_gemm_ctx<<<dim3(8, 16, 4), 256, 0, stream>>>(pb, vt, ctx);
}

// Round 11
// 366.655 us; speedup vs baseline: 1.0616x; 1.0616x over previous
//
#include <hip/hip_runtime.h>
#include <cstdint>
#include <cstddef>

// CausalAttention B=4 S=2048 D=1024.
// d_out = [context (4*2048*1024 f32)] ++ [attn_scores (4*2048*2048 f32)]
//
// scores = x M x^T, M[d,e] = sum_i Wq[d,i] Wk[e,i]:
//   M^T = bt(A=Wk, B=Wq)   (split bf16 3-pass; mu fused via atomics)
//   N~  = x M - sq*mu^T    (split; mean-deflated)
//   S   = N~ x^T + sq*u    (split, lower-tri; exact f32 rank-1 add-back)
// Round-11: (a) m-GEMM was a 64-block 25%-fill straggler at 1 block/CU —
// the one place barrier latency is unhidden (no co-resident overlap);
// now 256 tiles of 64x64 with BK=64 k-planes (full fill, 16 barriers).
// (b) n reverted to BK=32 (r10 showed BK=64 neutral at 2 blocks/CU —
// cross-block overlap already hides drains). sv noise floor is +-8 us.

#define S_LEN 2048
#define D_DIM 1024
#define NBATCH 4
#define MEG (1024 * 1024)

typedef __attribute__((ext_vector_type(4))) float floatx4;
typedef __attribute__((ext_vector_type(8))) __bf16 bf16x8;
typedef __attribute__((ext_vector_type(8))) short short8v;

__device__ __forceinline__ unsigned short f2bf(float f) {
  union { float f; unsigned u; } v; v.f = f;
  unsigned r = v.u + 0x7FFF + ((v.u >> 16) & 1);   // round-to-nearest-even
  return (unsigned short)(r >> 16);
}
__device__ __forceinline__ float bf2f(unsigned short h) {
  union { unsigned u; float f; } v; v.u = ((unsigned)h) << 16; return v.f;
}

__device__ __forceinline__ void async_copy16(const void* g, void* l) {
  __builtin_amdgcn_global_load_lds(
      (const __attribute__((address_space(1))) void*)g,
      (__attribute__((address_space(3))) void*)l, 16, 0, 0);
}

// ================= 256-thread, 128x128-tile cores (BK=32) =================

__device__ __forceinline__ void gemm_bt_core(
    const short* __restrict__ A, const short* __restrict__ B,
    int lda, int ldb, int kIters, int blockM, int blockN,
    short (*As)[32], short (*Bs)[32], floatx4 (&acc)[4][4])
{
  const int tid  = threadIdx.x;
  const int lane = tid & 63;
  const int wave = tid >> 6;
  const int wm = (wave >> 1) * 64;
  const int wn = (wave & 1) * 64;
  const int fm = lane & 15;
  const int fk = (lane >> 4) * 8;
  const int r0 = tid >> 2;
  const int c0 = (tid & 3) * 8;

  floatx4 zero = {0.f, 0.f, 0.f, 0.f};
  #pragma unroll
  for (int i = 0; i < 4; ++i)
    #pragma unroll
    for (int j = 0; j < 4; ++j)
      acc[i][j] = zero;

  const short* a0 = A + (size_t)(blockM + r0) * lda + c0;
  const short* a1 = a0 + (size_t)64 * lda;
  const short* b0 = B + (size_t)(blockN + r0) * ldb + c0;
  const short* b1 = b0 + (size_t)64 * ldb;
  short* as0 = &As[r0][c0];
  short* as1 = &As[r0 + 64][c0];
  short* bs0 = &Bs[r0][c0];
  short* bs1 = &Bs[r0 + 64][c0];

  for (int kt = 0; kt < kIters; ++kt) {
    const int kb = kt * 32;
    async_copy16(a0 + kb, as0);
    async_copy16(a1 + kb, as1);
    async_copy16(b0 + kb, bs0);
    async_copy16(b1 + kb, bs1);
    __syncthreads();
    bf16x8 af[4], bfr[4];
    #pragma unroll
    for (int i = 0; i < 4; ++i)
      af[i] = *(const bf16x8*)(&As[wm + i * 16 + fm][fk]);
    #pragma unroll
    for (int j = 0; j < 4; ++j)
      bfr[j] = *(const bf16x8*)(&Bs[wn + j * 16 + fm][fk]);
    #pragma unroll
    for (int i = 0; i < 4; ++i)
      #pragma unroll
      for (int j = 0; j < 4; ++j)
        acc[i][j] = __builtin_amdgcn_mfma_f32_16x16x32_bf16(af[i], bfr[j], acc[i][j], 0, 0, 0);
    __syncthreads();
  }
}

__device__ __forceinline__ void gemm_bt_split_core(
    const short* __restrict__ Ah, const short* __restrict__ Al,
    const short* __restrict__ Bh, const short* __restrict__ Bl,
    int lda, int ldb, int kIters, int blockM, int blockN,
    short (*AsH)[32], short (*AsL)[32], short (*BsH)[32], short (*BsL)[32],
    floatx4 (&acc)[4][4])
{
  const int tid  = threadIdx.x;
  const int lane = tid & 63;
  const int wave = tid >> 6;
  const int wm = (wave >> 1) * 64;
  const int wn = (wave & 1) * 64;
  const int fm = lane & 15;
  const int fk = (lane >> 4) * 8;
  const int r0 = tid >> 2;
  const int c0 = (tid & 3) * 8;

  floatx4 zero = {0.f, 0.f, 0.f, 0.f};
  #pragma unroll
  for (int i = 0; i < 4; ++i)
    #pragma unroll
    for (int j = 0; j < 4; ++j)
      acc[i][j] = zero;

  const size_t oa0 = (size_t)(blockM + r0) * lda + c0;
  const size_t oa1 = oa0 + (size_t)64 * lda;
  const size_t ob0 = (size_t)(blockN + r0) * ldb + c0;
  const size_t ob1 = ob0 + (size_t)64 * ldb;
  short* lah0 = &AsH[r0][c0]; short* lah1 = &AsH[r0 + 64][c0];
  short* lal0 = &AsL[r0][c0]; short* lal1 = &AsL[r0 + 64][c0];
  short* lbh0 = &BsH[r0][c0]; short* lbh1 = &BsH[r0 + 64][c0];
  short* lbl0 = &BsL[r0][c0]; short* lbl1 = &BsL[r0 + 64][c0];

  for (int kt = 0; kt < kIters; ++kt) {
    const int kb = kt * 32;
    async_copy16(Ah + oa0 + kb, lah0);
    async_copy16(Ah + oa1 + kb, lah1);
    async_copy16(Al + oa0 + kb, lal0);
    async_copy16(Al + oa1 + kb, lal1);
    async_copy16(Bh + ob0 + kb, lbh0);
    async_copy16(Bh + ob1 + kb, lbh1);
    async_copy16(Bl + ob0 + kb, lbl0);
    async_copy16(Bl + ob1 + kb, lbl1);
    __syncthreads();
    bf16x8 ah[4], al[4], bh[4], bl[4];
    #pragma unroll
    for (int i = 0; i < 4; ++i) {
      ah[i] = *(const bf16x8*)(&AsH[wm + i * 16 + fm][fk]);
      al[i] = *(const bf16x8*)(&AsL[wm + i * 16 + fm][fk]);
    }
    #pragma unroll
    for (int j = 0; j < 4; ++j) {
      bh[j] = *(const bf16x8*)(&BsH[wn + j * 16 + fm][fk]);
      bl[j] = *(const bf16x8*)(&BsL[wn + j * 16 + fm][fk]);
    }
    #pragma unroll
    for (int i = 0; i < 4; ++i)
      #pragma unroll
      for (int j = 0; j < 4; ++j) {
        acc[i][j] = __builtin_amdgcn_mfma_f32_16x16x32_bf16(ah[i], bh[j], acc[i][j], 0, 0, 0);
        acc[i][j] = __builtin_amdgcn_mfma_f32_16x16x32_bf16(ah[i], bl[j], acc[i][j], 0, 0, 0);
        acc[i][j] = __builtin_amdgcn_mfma_f32_16x16x32_bf16(al[i], bh[j], acc[i][j], 0, 0, 0);
      }
    __syncthreads();
  }
}

// ---------------- W conversions ----------------
// [0,512): Wq split. [512,1024): Wk split. [1024,2048): Wv transpose (hi only);
// block 1024 also zeroes muSum.

__global__ __launch_bounds__(256) void k_cvt_w(
    const float* __restrict__ wq, const float* __restrict__ wk,
    const float* __restrict__ wv,
    short* __restrict__ wqh, short* __restrict__ wql,
    short* __restrict__ wkh, short* __restrict__ wkl,
    short* __restrict__ wvt, float* __restrict__ muSum)
{
  const int bid = blockIdx.x;
  const int tid = threadIdx.x;
  if (bid < 1024) {
    const float4* src;
    short *dh, *dl;
    size_t idx;
    if (bid < 512) {
      idx = (size_t)bid * 256 + tid;
      src = (const float4*)wq; dh = wqh; dl = wql;
    } else {
      idx = (size_t)(bid - 512) * 256 + tid;
      src = (const float4*)wk; dh = wkh; dl = wkl;
    }
    const float4 u4 = src[idx * 2];
    const float4 w4 = src[idx * 2 + 1];
    float f[8] = {u4.x, u4.y, u4.z, u4.w, w4.x, w4.y, w4.z, w4.w};
    short8v oh, ol;
    #pragma unroll
    for (int e = 0; e < 8; ++e) {
      const unsigned short h = f2bf(f[e]);
      oh[e] = (short)h;
      ol[e] = (short)f2bf(f[e] - bf2f(h));
    }
    *(short8v*)(dh + idx * 8) = oh;
    *(short8v*)(dl + idx * 8) = ol;
  } else {
    if (bid == 1024) {   // zero muSum before k_m_cvtx's atomics
      float4 z = {0.f, 0.f, 0.f, 0.f};
      ((float4*)muSum)[tid] = z;
    }
    const int rem = bid - 1024;
    const int bx = rem & 31, by = rem >> 5;
    const int tx = tid & 31, ty = tid >> 5;  // 32 x 8
    __shared__ float tile[32][33];
    const int colIn = bx * 32 + tx;
    #pragma unroll
    for (int i = 0; i < 4; ++i) {
      const int rowIn = by * 32 + ty + i * 8;
      tile[ty + i * 8][tx] = wv[(size_t)rowIn * D_DIM + colIn];
    }
    __syncthreads();
    const int colOut = by * 32 + tx;   // d (input row of Wv)
    #pragma unroll
    for (int i = 0; i < 4; ++i) {
      const int rowOut = bx * 32 + ty + i * 8;  // n (output col of Wv)
      wvt[(size_t)rowOut * D_DIM + colOut] = (short)f2bf(tile[tx][ty + i * 8]);
    }
  }
}

// ---------------- M^T GEMM (256 64x64 tiles, BK=64) + x split (4096), fused ----------------
// m tiles at FULL machine fill (1 tile/CU) with 16 barriers (BK=64 k-planes) —
// the 1-block/CU no-overlap case where barrier count is the wall.

__global__ __launch_bounds__(256) void k_m_cvtx(
    const short* __restrict__ wqh, const short* __restrict__ wql,
    const short* __restrict__ wkh, const short* __restrict__ wkl,
    short* __restrict__ mth, short* __restrict__ mtl,
    float* __restrict__ muSum,
    const float4* __restrict__ x,
    short* __restrict__ xh, short* __restrict__ xl)
{
  __shared__ alignas(16) short AsH[2][64][32];
  __shared__ alignas(16) short AsL[2][64][32];
  __shared__ alignas(16) short BsH[2][64][32];
  __shared__ alignas(16) short BsL[2][64][32];
  const int g = blockIdx.x;
  const int tid = threadIdx.x;

  if (g < 256) {
    // --- 64x64 M^T tile: A = Wk rows (e), B = Wq rows (d), inner = i ---
    floatx4 acc[2][2];
    const int blockM = (g >> 4) * 64;    // e
    const int blockN = (g & 15) * 64;    // d
    const int lane = tid & 63, wave = tid >> 6;
    const int wm = (wave >> 1) * 32, wn = (wave & 1) * 32;
    const int fm = lane & 15, fk = (lane >> 4) * 8;

    floatx4 zero = {0.f, 0.f, 0.f, 0.f};
    #pragma unroll
    for (int i = 0; i < 2; ++i)
      #pragma unroll
      for (int j = 0; j < 2; ++j)
        acc[i][j] = zero;

    // staging: plane p holds k-subrange p*32..p*32+31; chunk c = tid + 256*p
    const int sr = tid >> 2;             // row 0..63
    const int sc = (tid & 3) * 8;        // col 0..31 step 8
    const short* ah0 = wkh + (size_t)(blockM + sr) * D_DIM + sc;
    const short* al0 = wkl + (size_t)(blockM + sr) * D_DIM + sc;
    const short* bh0 = wqh + (size_t)(blockN + sr) * D_DIM + sc;
    const short* bl0 = wql + (size_t)(blockN + sr) * D_DIM + sc;
    short* ahB = &AsH[0][0][0]; short* alB = &AsL[0][0][0];
    short* bhB = &BsH[0][0][0]; short* blB = &BsL[0][0][0];
    const int l0 = tid * 8, l1 = (tid + 256) * 8;

    for (int kt = 0; kt < 16; ++kt) {    // BK=64
      const int kb = kt * 64;
      async_copy16(ah0 + kb, ahB + l0);
      async_copy16(ah0 + kb + 32, ahB + l1);
      async_copy16(al0 + kb, alB + l0);
      async_copy16(al0 + kb + 32, alB + l1);
      async_copy16(bh0 + kb, bhB + l0);
      async_copy16(bh0 + kb + 32, bhB + l1);
      async_copy16(bl0 + kb, blB + l0);
      async_copy16(bl0 + kb + 32, blB + l1);
      __syncthreads();
      #pragma unroll
      for (int ks = 0; ks < 2; ++ks) {
        bf16x8 ah[2], al[2], bh[2], bl[2];
        #pragma unroll
        for (int i = 0; i < 2; ++i) {
          ah[i] = *(const bf16x8*)(&AsH[ks][wm + i * 16 + fm][fk]);
          al[i] = *(const bf16x8*)(&AsL[ks][wm + i * 16 + fm][fk]);
        }
        #pragma unroll
        for (int j = 0; j < 2; ++j) {
          bh[j] = *(const bf16x8*)(&BsH[ks][wn + j * 16 + fm][fk]);
          bl[j] = *(const bf16x8*)(&BsL[ks][wn + j * 16 + fm][fk]);
        }
        #pragma unroll
        for (int i = 0; i < 2; ++i)
          #pragma unroll
          for (int j = 0; j < 2; ++j) {
            acc[i][j] = __builtin_amdgcn_mfma_f32_16x16x32_bf16(ah[i], bh[j], acc[i][j], 0, 0, 0);
            acc[i][j] = __builtin_amdgcn_mfma_f32_16x16x32_bf16(ah[i], bl[j], acc[i][j], 0, 0, 0);
            acc[i][j] = __builtin_amdgcn_mfma_f32_16x16x32_bf16(al[i], bh[j], acc[i][j], 0, 0, 0);
          }
      }
      __syncthreads();
    }

    const int rb = wm + ((lane >> 4) << 2);
    const int cb = wn + (lane & 15);
    #pragma unroll
    for (int i = 0; i < 2; ++i)
      #pragma unroll
      for (int j = 0; j < 2; ++j) {
        const int n = blockN + cb + j * 16;
        #pragma unroll
        for (int r = 0; r < 2 * 2; ++r) {
          const int m = blockM + rb + i * 16 + r;
          const float f = acc[i][j][r];
          const unsigned short h = f2bf(f);
          mth[(size_t)m * D_DIM + n] = (short)h;
          mtl[(size_t)m * D_DIM + n] = (short)f2bf(f - bf2f(h));
        }
      }
    // mu partials: per row e, sum over this block's 64 d-cols
    #pragma unroll
    for (int i = 0; i < 2; ++i)
      #pragma unroll
      for (int r = 0; r < 4; ++r) {
        float v = acc[i][0][r] + acc[i][1][r];
        v += __shfl_xor(v, 1); v += __shfl_xor(v, 2);
        v += __shfl_xor(v, 4); v += __shfl_xor(v, 8);
        if ((lane & 15) == 0)
          atomicAdd(&muSum[blockM + rb + i * 16 + r], v);
      }
  } else {
    const size_t idx = (size_t)(g - 256) * 256 + tid;
    const float4 u4 = x[idx * 2];
    const float4 w4 = x[idx * 2 + 1];
    float f[8] = {u4.x, u4.y, u4.z, u4.w, w4.x, w4.y, w4.z, w4.w};
    short8v oh, ol;
    #pragma unroll
    for (int e = 0; e < 8; ++e) {
      const unsigned short h = f2bf(f[e]);
      oh[e] = (short)h;
      ol[e] = (short)f2bf(f[e] - bf2f(h));
    }
    *(short8v*)(xh + idx * 8) = oh;
    *(short8v*)(xl + idx * 8) = ol;
  }
}

// ---------------- per-row stats over reconstructed split-x ----------------

__global__ __launch_bounds__(256) void k_rowstats(
    const short* __restrict__ xh, const short* __restrict__ xl,
    const float* __restrict__ muSum, float* __restrict__ sq, float* __restrict__ u)
{
  const int r = blockIdx.x, tid = threadIdx.x;
  const ushort4 h = *(const ushort4*)(xh + (size_t)r * D_DIM + tid * 4);
  const ushort4 l = *(const ushort4*)(xl + (size_t)r * D_DIM + tid * 4);
  const float4 m4 = *(const float4*)(muSum + tid * 4);
  const float x0 = bf2f(h.x) + bf2f(l.x);
  const float x1 = bf2f(h.y) + bf2f(l.y);
  const float x2 = bf2f(h.z) + bf2f(l.z);
  const float x3 = bf2f(h.w) + bf2f(l.w);
  float s = x0 + x1 + x2 + x3;
  float uu = m4.x * x0 + m4.y * x1 + m4.z * x2 + m4.w * x3;
  #pragma unroll
  for (int off = 32; off > 0; off >>= 1) {
    s  += __shfl_xor(s, off);
    uu += __shfl_xor(uu, off);
  }
  __shared__ float ps[4], pu[4];
  if ((tid & 63) == 0) { ps[tid >> 6] = s; pu[tid >> 6] = uu; }
  __syncthreads();
  if (tid == 0) {
    sq[r] = ps[0] + ps[1] + ps[2] + ps[3];
    u[r]  = (pu[0] + pu[1] + pu[2] + pu[3]) * (1.0f / 1024.0f);
  }
}

// ---------------- N~ = x M - sq mu^T, split hi/lo (BK=32, r9 known-good) ----------------

__global__ __launch_bounds__(256) void k_gemm_n(
    const short* __restrict__ xh, const short* __restrict__ xl,
    const short* __restrict__ mth, const short* __restrict__ mtl,
    const float* __restrict__ sq, const float* __restrict__ muSum,
    short* __restrict__ nh, short* __restrict__ nl)
{
  __shared__ alignas(16) short AsH[128][32];
  __shared__ alignas(16) short AsL[128][32];
  __shared__ alignas(16) short BsH[128][32];
  __shared__ alignas(16) short BsL[128][32];
  floatx4 acc[4][4];
  const int blockM = blockIdx.y * 128;   // global row (b,s)
  const int blockN = blockIdx.x * 128;   // e
  gemm_bt_split_core(xh, xl, mth, mtl, D_DIM, D_DIM, D_DIM / 32,
                     blockM, blockN, AsH, AsL, BsH, BsL, acc);

  const int tid = threadIdx.x, lane = tid & 63, wave = tid >> 6;
  const int wm = (wave >> 1) * 64, wn = (wave & 1) * 64;
  const int rb = wm + ((lane >> 4) << 2);
  const int cb = wn + (lane & 15);
  #pragma unroll
  for (int i = 0; i < 4; ++i)
    #pragma unroll
    for (int j = 0; j < 4; ++j) {
      const int n = blockN + cb + j * 16;
      const float muv = muSum[n] * (1.0f / 1024.0f);
      #pragma unroll
      for (int r = 0; r < 4; ++r) {
        const int m = blockM + rb + i * 16 + r;
        const float f = acc[i][j][r] - sq[m] * muv;   // deflate
        const unsigned short h = f2bf(f);
        nh[(size_t)m * D_DIM + n] = (short)h;
        nl[(size_t)m * D_DIM + n] = (short)f2bf(f - bf2f(h));
      }
    }
}

// ---------------- fused scores (544, band-ordered) + V (512, tail filler) ----------------

__global__ __launch_bounds__(256) void k_gemm_sv(
    const short* __restrict__ nh, const short* __restrict__ nl,
    const short* __restrict__ xh, const short* __restrict__ xl,
    const float* __restrict__ sq, const float* __restrict__ u,
    const short* __restrict__ wvt, float* __restrict__ attn,
    short* __restrict__ vt)
{
  __shared__ alignas(16) short AsH[128][32];
  __shared__ alignas(16) short AsL[128][32];
  __shared__ alignas(16) short BsH[128][32];
  __shared__ alignas(16) short BsL[128][32];
  floatx4 acc[4][4];

  const int g = blockIdx.x;
  const int tid = threadIdx.x, lane = tid & 63, wave = tid >> 6;
  const int wm = (wave >> 1) * 64, wn = (wave & 1) * 64;
  const int rb = wm + ((lane >> 4) << 2);
  const int cb = wn + (lane & 15);

  if (g < 544) {
    const int item = (g & 7) * 68 + (g >> 3);   // per-XCD chunk (batch = 2 XCDs)
    const int b = item / 136;
    int t = item - b * 136;
    int band = 0;
    while (t >= 58 - 16 * band) { t -= 58 - 16 * band; ++band; }
    int bi = band * 4;
    for (;;) {
      const int w = bi - band * 4 + 1;
      const int ww = w < 4 ? w : 4;
      if (t < ww) break;
      t -= ww; ++bi;
    }
    const int bj = band * 4 + t;

    const size_t boff = (size_t)b * S_LEN * D_DIM;
    gemm_bt_split_core(nh + boff, nl + boff, xh + boff, xl + boff,
                       D_DIM, D_DIM, D_DIM / 32, bi * 128, bj * 128,
                       AsH, AsL, BsH, BsL, acc);

    float* out = attn + (size_t)b * S_LEN * S_LEN;
    const int rowBase = (b << 11) + bi * 128;
    const int colBase = (b << 11) + bj * 128;
    #pragma unroll
    for (int j = 0; j < 4; ++j) {
      const int n = bj * 128 + cb + j * 16;
      const float uv = u[colBase + cb + j * 16];
      #pragma unroll
      for (int i = 0; i < 4; ++i)
        #pragma unroll
        for (int r = 0; r < 4; ++r) {
          const int m = bi * 128 + rb + i * 16 + r;
          const float sv = sq[rowBase + rb + i * 16 + r];
          out[(size_t)m * S_LEN + n] = acc[i][j][r] + sv * uv;  // raw scores
        }
    }
  } else {
    const int vb = g - 544;
    const int blockM = (vb >> 3) * 128;   // global row over 8192
    const int blockN = (vb & 7) * 128;    // d
    gemm_bt_core(xh, wvt, D_DIM, D_DIM, D_DIM / 32, blockM, blockN,
                 AsH, BsH, acc);
    #pragma unroll
    for (int i = 0; i < 4; ++i)
      #pragma unroll
      for (int j = 0; j < 4; ++j) {
        const int n = blockN + cb + j * 16;   // d index
        const int m0 = blockM + rb + i * 16;  // global row, 4-aligned
        const int b = m0 >> 11;
        const int s0 = m0 & (S_LEN - 1);
        ushort4 pk;
        pk.x = f2bf(acc[i][j][0]); pk.y = f2bf(acc[i][j][1]);
        pk.z = f2bf(acc[i][j][2]); pk.w = f2bf(acc[i][j][3]);
        *(ushort4*)(vt + ((size_t)b * D_DIM + n) * S_LEN + s0) = pk;
      }
  }
}

// ---------------- softmax: prefix-only reads, band-limited pb writes ----------------

__global__ __launch_bounds__(256) void k_softmax(float* __restrict__ attn,
                                                 short* __restrict__ pb) {
  const int b = blockIdx.x >> 11;
  const int q = blockIdx.x & (S_LEN - 1);
  float* row  = attn + ((size_t)b * S_LEN + q) * S_LEN;
  short* prow = pb   + ((size_t)b * S_LEN + q) * S_LEN;
  const int tid = threadIdx.x;
  const int k0 = tid * 8;
  const int kBand = ((q >> 7) + 1) << 7;   // 128-aligned band end
  __shared__ float sMax[4], sSum[4];

  float v[8];
  if (k0 <= q) {               // load only the live prefix
    const float4 a0 = *(const float4*)(row + k0);
    const float4 a1 = *(const float4*)(row + k0 + 4);
    v[0] = a0.x; v[1] = a0.y; v[2] = a0.z; v[3] = a0.w;
    v[4] = a1.x; v[5] = a1.y; v[6] = a1.z; v[7] = a1.w;
  } else {
    #pragma unroll
    for (int e = 0; e < 8; ++e) v[e] = -3.0e38f;
  }

  float mx = -3.0e38f;
  #pragma unroll
  for (int e = 0; e < 8; ++e) {
    v[e] = (k0 + e <= q) ? v[e] : -3.0e38f;
    mx = fmaxf(mx, v[e]);
  }
  #pragma unroll
  for (int off = 32; off > 0; off >>= 1) mx = fmaxf(mx, __shfl_xor(mx, off));
  if ((tid & 63) == 0) sMax[tid >> 6] = mx;
  __syncthreads();
  mx = fmaxf(fmaxf(sMax[0], sMax[1]), fmaxf(sMax[2], sMax[3]));

  float s = 0.f;
  #pragma unroll
  for (int e = 0; e < 8; ++e) {
    const float p = (k0 + e <= q) ? __expf((v[e] - mx) * 0.03125f) : 0.f;
    v[e] = p;
    s += p;
  }
  #pragma unroll
  for (int off = 32; off > 0; off >>= 1) s += __shfl_xor(s, off);
  if ((tid & 63) == 0) sSum[tid >> 6] = s;
  __syncthreads();
  s = sSum[0] + sSum[1] + sSum[2] + sSum[3];
  const float inv = 1.0f / s;

  float o[8];
  #pragma unroll
  for (int e = 0; e < 8; ++e) o[e] = v[e] * inv;   // 0 for masked
  float4 w0 = {o[0], o[1], o[2], o[3]};
  float4 w1 = {o[4], o[5], o[6], o[7]};
  *(float4*)(row + k0) = w0;
  *(float4*)(row + k0 + 4) = w1;
  if (k0 < kBand) {
    ushort4 p0, p1;
    p0.x = f2bf(o[0]); p0.y = f2bf(o[1]); p0.z = f2bf(o[2]); p0.w = f2bf(o[3]);
    p1.x = f2bf(o[4]); p1.y = f2bf(o[5]); p1.z = f2bf(o[6]); p1.w = f2bf(o[7]);
    *(ushort4*)(prow + k0) = p0;
    *(ushort4*)(prow + k0 + 4) = p1;
  }
}

// ---------------- context = P @ V, 128^2, BK=64 k-plane LDS, heavy first ----------------

__global__ __launch_bounds__(256) void k_gemm_ctx(
    const short* __restrict__ pb, const short* __restrict__ vt,
    float* __restrict__ ctx)
{
  __shared__ alignas(16) short As2[2][128][32];
  __shared__ alignas(16) short Bs2[2][128][32];
  floatx4 acc[4][4];
  const int b = blockIdx.z;
  const int by = 15 - blockIdx.y;        // heavy K-loops dispatched first
  const int blockM = by * 128;           // q
  const int blockN = blockIdx.x * 128;   // d
  const int kIters = (by + 1) * 2;       // BK=64; k <= blockM+127 only
  const short* A = pb + (size_t)b * S_LEN * S_LEN;
  const short* B = vt + (size_t)b * D_DIM * S_LEN;

  const int tid = threadIdx.x, lane = tid & 63, wave = tid >> 6;
  const int wm = (wave >> 1) * 64, wn = (wave & 1) * 64;
  const int fm = lane & 15, fk = (lane >> 4) * 8;
  const int r0 = tid >> 2, c0 = (tid & 3) * 8;

  floatx4 zero = {0.f, 0.f, 0.f, 0.f};
  #pragma unroll
  for (int i = 0; i < 4; ++i)
    #pragma unroll
    for (int j = 0; j < 4; ++j)
      acc[i][j] = zero;

  const short* a0 = A + (size_t)(blockM + r0) * S_LEN + c0;
  const short* a1 = a0 + (size_t)64 * S_LEN;
  const short* b0 = B + (size_t)(blockN + r0) * S_LEN + c0;
  const short* b1 = b0 + (size_t)64 * S_LEN;
  short* asBase = &As2[0][0][0];
  short* bsBase = &Bs2[0][0][0];
  short* as0 = asBase + (size_t)tid * 8;
  short* as1 = asBase + (size_t)(tid + 256) * 8;
  short* as2 = asBase + (size_t)(tid + 512) * 8;
  short* as3 = asBase + (size_t)(tid + 768) * 8;
  short* bs0 = bsBase + (size_t)tid * 8;
  short* bs1 = bsBase + (size_t)(tid + 256) * 8;
  short* bs2 = bsBase + (size_t)(tid + 512) * 8;
  short* bs3 = bsBase + (size_t)(tid + 768) * 8;

  for (int kt = 0; kt < kIters; ++kt) {
    const int kb = kt * 64;
    async_copy16(a0 + kb, as0);
    async_copy16(a1 + kb, as1);
    async_copy16(a0 + kb + 32, as2);
    async_copy16(a1 + kb + 32, as3);
    async_copy16(b0 + kb, bs0);
    async_copy16(b1 + kb, bs1);
    async_copy16(b0 + kb + 32, bs2);
    async_copy16(b1 + kb + 32, bs3);
    __syncthreads();
    #pragma unroll
    for (int ks = 0; ks < 2; ++ks) {
      bf16x8 af[4], bfr[4];
      #pragma unroll
      for (int i = 0; i < 4; ++i)
        af[i] = *(const bf16x8*)(&As2[ks][wm + i * 16 + fm][fk]);
      #pragma unroll
      for (int j = 0; j < 4; ++j)
        bfr[j] = *(const bf16x8*)(&Bs2[ks][wn + j * 16 + fm][fk]);
      #pragma unroll
      for (int i = 0; i < 4; ++i)
        #pragma unroll
        for (int j = 0; j < 4; ++j)
          acc[i][j] = __builtin_amdgcn_mfma_f32_16x16x32_bf16(af[i], bfr[j], acc[i][j], 0, 0, 0);
    }
    __syncthreads();
  }

  float* out = ctx + (size_t)b * S_LEN * D_DIM;
  const int rb = wm + ((lane >> 4) << 2);
  const int cb = wn + (lane & 15);
  #pragma unroll
  for (int i = 0; i < 4; ++i)
    #pragma unroll
    for (int j = 0; j < 4; ++j) {
      const int n = blockN + cb + j * 16;
      #pragma unroll
      for (int r = 0; r < 4; ++r) {
        const int m = blockM + rb + i * 16 + r;
        out[(size_t)m * D_DIM + n] = acc[i][j][r];
      }
    }
}

// ---------------- launch ----------------

extern "C" void kernel_launch(void* const* d_in, const int* in_sizes, int n_in,
                              void* d_out, int out_size, void* d_ws, size_t ws_size,
                              hipStream_t stream) {
  const float* x  = (const float*)d_in[0];
  const float* wq = (const float*)d_in[1];
  const float* wk = (const float*)d_in[2];
  const float* wv = (const float*)d_in[3];

  float* out  = (float*)d_out;
  float* ctx  = out;                                       // [4,2048,1024]
  float* attn = out + (size_t)NBATCH * S_LEN * D_DIM;      // [4,2048,2048]

  // workspace (shorts), ~94 MiB; pb aliases nh/nl (dead after scores GEMM)
  short* ws  = (short*)d_ws;
  short* xh  = ws;                                  // 8M
  short* xl  = xh + (size_t)8 * MEG;                // 8M
  short* wqh = xl + (size_t)8 * MEG;                // 1M Wq hi (original layout)
  short* wql = wqh + (size_t)1 * MEG;               // 1M Wq lo
  short* wkh = wql + (size_t)1 * MEG;               // 1M Wk hi
  short* wkl = wkh + (size_t)1 * MEG;               // 1M Wk lo
  short* wvt = wkl + (size_t)1 * MEG;               // 1M Wv^T hi
  short* mth = wvt + (size_t)1 * MEG;               // 1M M^T hi
  short* mtl = mth + (size_t)1 * MEG;               // 1M M^T lo
  short* nh  = mtl + (size_t)1 * MEG;               // 8M N~ hi
  short* nl  = nh + (size_t)8 * MEG;                // 8M N~ lo
  short* vt  = nl + (size_t)8 * MEG;                // 8M V^T [b,d,s]
  short* pb  = nh;                                  // 16M alias (nh+nl)
  float* fb  = (float*)(vt + (size_t)8 * MEG);
  float* muS = fb;                                  // 1024 (sum over d, not mean)
  float* sq  = fb + 1024;                           // 8192
  float* u   = sq + 8192;                           // 8192

  k_cvt_w<<<2048, 256, 0, stream>>>(wq, wk, wv, wqh, wql, wkh, wkl, wvt, muS);
  k_m_cvtx<<<4352, 256, 0, stream>>>(wqh, wql, wkh, wkl, mth, mtl, muS,
                                     (const float4*)x, xh, xl);
  k_rowstats<<<8192, 256, 0, stream>>>(xh, xl, muS, sq, u);
  k_gemm_n<<<dim3(8, 64), 256, 0, stream>>>(xh, xl, mth, mtl, sq, muS, nh, nl);
  k_gemm_sv<<<1056, 256, 0, stream>>>(nh, nl, xh, xl, sq, u, wvt, attn, vt);
  k_softmax<<<NBATCH * S_LEN, 256, 0, stream>>>(attn, pb);
  k_gemm_ctx<<<dim3(8, 16, 4), 256, 0, stream>>>(pb, vt, ctx);
}